// Round 5
// baseline (312.676 us; speedup 1.0000x reference)
//
#include <hip/hip_runtime.h>

// DynamicAttention on MI355X (gfx950).
// Pipeline (single-pass softmaxes — scores are O(5) so exp() needs no max shift):
//   1) x -> fp16, W -> fp16 transposed ([n][k] row-major)
//   2) 9 projections via fp16 MFMA GEMM (fp32 accum)
//   3) v -> vt (transposed) for the PV GEMM B-operand
//   4) boundary scores: one pass, e = exp(sc) f16 (left->eL lower tri, right->eR upper tri)
//   5) per-row prefix/suffix scan -> att_mask f16 into eL
//   6) final score: ping-pong pipelined (counted vmcnt(8)), XCD-chunked block swizzle
//      (each XCD owns 4 contiguous rbk rows -> A-panels L2-resident), s_setprio
//      around MFMA clusters; mask tile staged to LDS overlapped with last MFMA
//   7) PV: split-K=4 GEMM, 128x64 tiles (grid 1024, 4 blocks/CU all-resident,
//      bit-identical accumulation order vs 128x128 version)
//   8) k_fin: att_weight = ehalf/lsc; O = sum(bf16 partials)/lsc
//
// Round-2 lesson: direct-global MFMA fragments collapse (TA-bound, 8% MfmaUtil).
// Round-3 lesson: 64x64 wave tiles (less LDS traffic) regress -> not LDS-BW-bound.
// Round-4 lesson: 512-thr/16-wave k_score regresses -> phase overhead amortization
// (32 MFMA/wave/phase) beats raw TLP; k_score is register-capped at 2 waves/SIMD
// (128 acc + ~120 VGPR = 248 unified), so occupancy axis is closed there.

#define SS 4096
#define DD 512
#define INV_NORM 0.04419417382415922f  // 1/sqrt(512)

typedef _Float16 f16;
typedef f16 f16x8 __attribute__((ext_vector_type(8)));
typedef f16 f16x4 __attribute__((ext_vector_type(4)));
typedef float f32x4 __attribute__((ext_vector_type(4)));
typedef unsigned short ushort;
typedef ushort ushort4v __attribute__((ext_vector_type(4)));

#define GAS __attribute__((address_space(1)))
#define LAS __attribute__((address_space(3)))

// raw barrier + counted vmcnt (compiler memory fences via asm clobber)
#define BARM() asm volatile("s_barrier" ::: "memory")
#define WAITV(N) asm volatile("s_waitcnt vmcnt(" #N ")" ::: "memory")

__device__ __forceinline__ void ldsdma16(const void* g, void* l) {
  __builtin_amdgcn_global_load_lds((const GAS void*)g, (LAS void*)l, 16, 0, 0);
}

__device__ __forceinline__ ushort f2bf(float f) {  // round-to-nearest-even bf16
  unsigned u = __float_as_uint(f);
  return (ushort)((u + 0x7FFFu + ((u >> 16) & 1u)) >> 16);
}
__device__ __forceinline__ float bf2f(ushort h) {
  return __uint_as_float((unsigned)h << 16);
}

// Stage a 128x64 f16 tile (rows x k) from row-major [*, ldk] global into LDS.
// 16B-chunk XOR swizzle: logical chunk q of row r stored at slot (q ^ (r&7)).
__device__ __forceinline__ void stage16(const f16* __restrict__ src, int ldk, f16* lds, int k0) {
  const int tid  = threadIdx.x;
  const int lane = tid & 63;
  const int wv   = tid >> 6;
  const int rb   = wv * 8 + (lane >> 3);
  const int cs   = lane & 7;
#pragma unroll
  for (int c = 0; c < 4; ++c) {
    const int r = c * 32 + rb;
    const int q = cs ^ (r & 7);
    ldsdma16(src + (size_t)r * ldk + k0 + q * 8, lds + c * 2048 + wv * 512);
  }
}

// 64-row variant: stage a 64x64 f16 tile (same layout, rows 0..63).
__device__ __forceinline__ void stage16h(const f16* __restrict__ src, int ldk, f16* lds, int k0) {
  const int tid  = threadIdx.x;
  const int lane = tid & 63;
  const int wv   = tid >> 6;
  const int rb   = wv * 8 + (lane >> 3);
  const int cs   = lane & 7;
#pragma unroll
  for (int c = 0; c < 2; ++c) {
    const int r = c * 32 + rb;
    const int q = cs ^ (r & 7);
    ldsdma16(src + (size_t)r * ldk + k0 + q * 8, lds + c * 2048 + wv * 512);
  }
}

// MFMA fragment load: lane holds [m=lane&15][k=(lane>>4)*8 + 0..7].
__device__ __forceinline__ f16x8 fragld(const f16* lds, int r0, int qb) {
  const int lane = threadIdx.x & 63;
  const int r = r0 + (lane & 15);
  const int q = (qb + (lane >> 4)) ^ (r & 7);
  return *(const f16x8*)(lds + r * 64 + q * 8);
}

// Accumulate one BK=64 step: this wave's 32 rows x 128 cols (2x8 16x16 fragments).
__device__ __forceinline__ void mma64(const f16* As, const f16* Bs, f32x4 acc[2][8]) {
  const int wv = threadIdx.x >> 6;
#pragma unroll
  for (int ks = 0; ks < 2; ++ks) {
    const f16x8 a0 = fragld(As, wv * 32,      ks * 4);
    const f16x8 a1 = fragld(As, wv * 32 + 16, ks * 4);
#pragma unroll
    for (int j = 0; j < 8; ++j) {
      const f16x8 b = fragld(Bs, j * 16, ks * 4);
      acc[0][j] = __builtin_amdgcn_mfma_f32_16x16x32_f16(a0, b, acc[0][j], 0, 0, 0);
      acc[1][j] = __builtin_amdgcn_mfma_f32_16x16x32_f16(a1, b, acc[1][j], 0, 0, 0);
    }
  }
}

// 32x64 wave tile against a 64-row B tile (k_pv 128x64 blocks).
__device__ __forceinline__ void mma3264(const f16* As, const f16* Bs, f32x4 acc[2][4]) {
  const int wv = threadIdx.x >> 6;
#pragma unroll
  for (int ks = 0; ks < 2; ++ks) {
    const f16x8 a0 = fragld(As, wv * 32,      ks * 4);
    const f16x8 a1 = fragld(As, wv * 32 + 16, ks * 4);
#pragma unroll
    for (int j = 0; j < 4; ++j) {
      const f16x8 b = fragld(Bs, j * 16, ks * 4);
      acc[0][j] = __builtin_amdgcn_mfma_f32_16x16x32_f16(a0, b, acc[0][j], 0, 0, 0);
      acc[1][j] = __builtin_amdgcn_mfma_f32_16x16x32_f16(a1, b, acc[1][j], 0, 0, 0);
    }
  }
}

// ---------------------------------------------------------------- conversions
__global__ void k_cvt_x(const float* __restrict__ x, f16* __restrict__ xh) {
  const size_t i = ((size_t)blockIdx.x * 256 + threadIdx.x) * 4;
  const float4 f = *(const float4*)(x + i);
  f16x4 h = { (f16)f.x, (f16)f.y, (f16)f.z, (f16)f.w };
  *(f16x4*)(xh + i) = h;
}

__global__ void k_trw(const float* w0, const float* w1, const float* w2, const float* w3,
                      const float* w4, const float* w5, const float* w6, const float* w7,
                      const float* w8, f16* __restrict__ wt) {
  const float* srcs[9] = {w0, w1, w2, w3, w4, w5, w6, w7, w8};
  const float* src = srcs[blockIdx.z];
  f16* dst = wt + (size_t)blockIdx.z * DD * DD;
  __shared__ float t[32][33];
  const int n0 = blockIdx.x * 32, k0 = blockIdx.y * 32;
  const int tx = threadIdx.x, ty = threadIdx.y;
#pragma unroll
  for (int i = 0; i < 32; i += 8)
    t[ty + i][tx] = src[(size_t)(k0 + ty + i) * DD + n0 + tx];
  __syncthreads();
#pragma unroll
  for (int i = 0; i < 32; i += 8)
    dst[(size_t)(n0 + ty + i) * DD + k0 + tx] = (f16)t[tx][ty + i];
}

__global__ void k_trv(const f16* __restrict__ v, f16* __restrict__ vt) {
  __shared__ f16 t[32][33];
  const int n0 = blockIdx.x * 32, s0 = blockIdx.y * 32;
  const int tx = threadIdx.x, ty = threadIdx.y;
#pragma unroll
  for (int i = 0; i < 32; i += 8)
    t[ty + i][tx] = v[(size_t)(s0 + ty + i) * DD + n0 + tx];
  __syncthreads();
#pragma unroll
  for (int i = 0; i < 32; i += 8)
    vt[(size_t)(n0 + ty + i) * SS + s0 + tx] = t[tx][ty + i];
}

// ---------------------------------------------------------------- projections
__global__ __launch_bounds__(256, 3) void k_proj(const f16* __restrict__ xh,
                                                 const f16* __restrict__ wt,
                                                 f16* __restrict__ proj) {
  __shared__ __align__(16) f16 As[8192];
  __shared__ __align__(16) f16 Bs[8192];
  const int z = blockIdx.z;
  const f16* B = wt + (size_t)z * DD * DD;
  f16* C = proj + (size_t)z * SS * DD;
  const int R0 = blockIdx.y * 128, C0 = blockIdx.x * 128;
  f32x4 acc[2][8];
#pragma unroll
  for (int i = 0; i < 2; ++i)
#pragma unroll
    for (int j = 0; j < 8; ++j) acc[i][j] = (f32x4){0.f, 0.f, 0.f, 0.f};
  for (int kb = 0; kb < DD / 64; ++kb) {
    __syncthreads();
    stage16(xh + (size_t)R0 * DD, DD, As, kb * 64);
    stage16(B  + (size_t)C0 * DD, DD, Bs, kb * 64);
    __syncthreads();
    mma64(As, Bs, acc);
  }
  const int lane = threadIdx.x & 63, wv = threadIdx.x >> 6;
  const int mm = lane & 15, quad = lane >> 4;
#pragma unroll
  for (int i = 0; i < 2; ++i)
#pragma unroll
    for (int j = 0; j < 8; ++j)
#pragma unroll
      for (int r = 0; r < 4; ++r)
        C[(size_t)(R0 + wv * 32 + i * 16 + quad * 4 + r) * DD + C0 + j * 16 + mm] =
            (f16)acc[i][j][r];
}

// ---------------------------------------------------------------- boundaries
// Compact triangular grid: 528 tiles per dir. dir 0 = left (valid c<=r, ->eL),
// dir 1 = right (valid c>=r, ->eR).  e = exp(sc) f16, no max shift (|sc| <~ 6).
__global__ __launch_bounds__(256, 3) void k_bnd(const f16* __restrict__ proj,
                                                f16* __restrict__ eL,
                                                f16* __restrict__ eR) {
  const int t = blockIdx.x, dir = blockIdx.y;
  int rbk = (int)((sqrtf(8.f * t + 1.f) - 1.f) * 0.5f);
  while ((rbk + 1) * (rbk + 2) / 2 <= t) ++rbk;
  while (rbk * (rbk + 1) / 2 > t) --rbk;
  int jt = t - rbk * (rbk + 1) / 2;           // jt <= rbk (lower triangle)
  if (dir) { jt = 31 - jt; rbk = 31 - rbk; }  // mirror -> jt >= rbk
  __shared__ __align__(16) f16 As[8192];
  __shared__ __align__(16) f16 Bs[8192];
  const f16* q  = proj + (size_t)(dir ? 2 : 0) * SS * DD;
  const f16* kp = proj + (size_t)(dir ? 3 : 1) * SS * DD;
  const int R0 = rbk * 128, C0 = jt * 128;
  f32x4 acc[2][8];
#pragma unroll
  for (int i = 0; i < 2; ++i)
#pragma unroll
    for (int j = 0; j < 8; ++j) acc[i][j] = (f32x4){0.f, 0.f, 0.f, 0.f};
  for (int kb = 0; kb < DD / 64; ++kb) {
    __syncthreads();
    stage16(q  + (size_t)R0 * DD, DD, As, kb * 64);
    stage16(kp + (size_t)C0 * DD, DD, Bs, kb * 64);
    __syncthreads();
    mma64(As, Bs, acc);
  }
  const int lane = threadIdx.x & 63, wv = threadIdx.x >> 6;
  const int mm = lane & 15, quad = lane >> 4;
  const bool diag = (jt == rbk);
  f16* outp = dir ? eR : eL;
#pragma unroll
  for (int i = 0; i < 2; ++i)
#pragma unroll
    for (int r = 0; r < 4; ++r) {
      const int rl = wv * 32 + i * 16 + quad * 4 + r;
#pragma unroll
      for (int j = 0; j < 8; ++j) {
        const int cl = j * 16 + mm;
        const float sc = acc[i][j][r] * INV_NORM;
        const bool bad = diag && (dir ? (cl < rl) : (cl > rl));
        const float e = bad ? 0.f : __expf(sc);
        outp[(size_t)(R0 + rl) * SS + (C0 + cl)] = (f16)e;
      }
    }
}

// ---------------------------------------------------------------- mask build
// One 1024-thread block per row i. Thread t owns f16x4 chunk at j=4t (coalesced).
// Loads are conditional: eL only where chunk intersects j<=i, eR only where j>=i.
__global__ __launch_bounds__(1024) void k_cumsum(f16* __restrict__ eL,
                                                 const f16* __restrict__ eR) {
  const int i = blockIdx.x;
  const int tid = threadIdx.x, lane = tid & 63, wv = tid >> 6;  // 16 waves
  __shared__ float wsL[16], wsR[16];
  const int j0 = tid * 4;

  // ---- left: e values valid for j<=i
  float pl[4] = {0.f, 0.f, 0.f, 0.f};
  if (j0 <= i) {
    const f16x4 hl = *(const f16x4*)(eL + (size_t)i * SS + j0);
#pragma unroll
    for (int u = 0; u < 4; ++u) pl[u] = (j0 + u <= i) ? (float)hl[u] : 0.f;
  }
#pragma unroll
  for (int u = 1; u < 4; ++u) pl[u] += pl[u - 1];
  const float Tl = pl[3];
  float sl = Tl;
#pragma unroll
  for (int d = 1; d < 64; d <<= 1) {
    const float o = __shfl_up(sl, (unsigned)d, 64);
    if (lane >= d) sl += o;
  }
  if (lane == 63) wsL[wv] = sl;

  // ---- right: e values valid for j>=i
  float rr[4] = {0.f, 0.f, 0.f, 0.f}, pr[4];
  if (j0 + 3 >= i) {
    const f16x4 hr = *(const f16x4*)(eR + (size_t)i * SS + j0);
#pragma unroll
    for (int u = 0; u < 4; ++u) rr[u] = (j0 + u >= i) ? (float)hr[u] : 0.f;
  }
  pr[0] = rr[0];
#pragma unroll
  for (int u = 1; u < 4; ++u) pr[u] = pr[u - 1] + rr[u];
  const float Tr = pr[3];
  float sr = Tr;
#pragma unroll
  for (int d = 1; d < 64; d <<= 1) {
    const float o = __shfl_up(sr, (unsigned)d, 64);
    if (lane >= d) sr += o;
  }
  if (lane == 63) wsR[wv] = sr;

  __syncthreads();
  float offL = 0.f, totL = 0.f, offR = 0.f, totR = 0.f;
#pragma unroll
  for (int ww = 0; ww < 16; ++ww) {
    const float a = wsL[ww], b = wsR[ww];
    if (ww < wv) { offL += a; offR += b; }
    totL += a; totR += b;
  }
  const float exL = offL + sl - Tl;        // exclusive prefix before this thread
  const float exR = offR + sr - Tr;
  const float invL = 1.f / totL, invR = 1.f / totR;

  f16x4 out;
#pragma unroll
  for (int u = 0; u < 4; ++u) {
    const int j = j0 + u;
    const float cdfL = (exL + pl[u]) * invL;                 // inclusive prefix
    const float pre  = exR + pr[u];
    const float cdfR = (totR - pre + rr[u]) * invR;          // inclusive suffix
    const float m = (j < i) ? cdfL : ((j > i) ? cdfR : 1.f);
    out[u] = (f16)m;
  }
  *(f16x4*)(eL + (size_t)i * SS + j0) = out;
}

// ---------------------------------------------------------------- final scores
// Single pass: sc = (qg.kg^T + (qloc.kloc^T)*mask)/norm; e=exp(sc) -> ehalf (f16);
// rowsum -> lsc via atomicAdd.
// Ping-pong pipeline (round-1 verified): G pair and L pair staged alternately
// with counted vmcnt(8); mask tile staged into dead Ag/Bg during final L-MFMA.
// Round-5 additions: XCD-chunked block swizzle (each XCD owns 4 contiguous rbk
// rows -> qg/ql A-panels stay L2-resident) + s_setprio around MFMA clusters.
__device__ __forceinline__ float mask_ld(const f16* Am, const f16* Bm, int r, int c) {
  const f16* b = (c < 64) ? Am : Bm;
  const int cc = c & 63;
  const int q = (cc >> 3) ^ (r & 7);
  return (float)b[r * 64 + q * 8 + (cc & 7)];
}

__global__ __launch_bounds__(256, 2) void k_score(const f16* __restrict__ proj,
                                                  const f16* __restrict__ mask,
                                                  f16* __restrict__ ehalf,
                                                  float* __restrict__ lsc) {
  __shared__ __align__(16) f16 Ag[8192];
  __shared__ __align__(16) f16 Bg[8192];
  __shared__ __align__(16) f16 Al[8192];
  __shared__ __align__(16) f16 Bl[8192];
  // XCD-chunked bijective swizzle: 1024 blocks = 8 XCDs x 128. Blocks with
  // lin%8==x dispatch to XCD x; give them the contiguous chunk [x*128,(x+1)*128)
  // = 4 rbk rows (all jt) so the 1 MB of A-panels stays in that XCD's L2.
  const int lin = blockIdx.y * 32 + blockIdx.x;
  const int swz = (lin & 7) * 128 + (lin >> 3);
  const int jt = swz & 31, rbk = swz >> 5;
  const f16* qg = proj + (size_t)4 * SS * DD;
  const f16* kg = proj + (size_t)5 * SS * DD;
  const f16* ql = proj + (size_t)6 * SS * DD;
  const f16* kl = proj + (size_t)7 * SS * DD;
  const int R0 = rbk * 128, C0 = jt * 128;
  f32x4 ag[2][8], al[2][8];
#pragma unroll
  for (int i = 0; i < 2; ++i)
#pragma unroll
    for (int j = 0; j < 8; ++j) {
      ag[i][j] = (f32x4){0.f, 0.f, 0.f, 0.f};
      al[i][j] = (f32x4){0.f, 0.f, 0.f, 0.f};
    }
  // prologue: both pairs for kb=0 in flight (16 outstanding/thread)
  stage16(qg + (size_t)R0 * DD, DD, Ag, 0);
  stage16(kg + (size_t)C0 * DD, DD, Bg, 0);
  stage16(ql + (size_t)R0 * DD, DD, Al, 0);
  stage16(kl + (size_t)C0 * DD, DD, Bl, 0);
  for (int kb = 0; kb < DD / 64 - 1; ++kb) {
    WAITV(8);           // G(kb) landed; L(kb) still in flight
    BARM();
    __builtin_amdgcn_s_setprio(1);
    mma64(Ag, Bg, ag);
    __builtin_amdgcn_s_setprio(0);
    BARM();             // all waves done reading G pair
    stage16(qg + (size_t)R0 * DD, DD, Ag, kb * 64 + 64);   // G(kb+1), flies over mma_l
    stage16(kg + (size_t)C0 * DD, DD, Bg, kb * 64 + 64);
    WAITV(8);           // L(kb) landed; G(kb+1) in flight
    BARM();
    __builtin_amdgcn_s_setprio(1);
    mma64(Al, Bl, al);
    __builtin_amdgcn_s_setprio(0);
    BARM();             // all waves done reading L pair
    stage16(ql + (size_t)R0 * DD, DD, Al, kb * 64 + 64);   // L(kb+1), flies over next mma_g
    stage16(kl + (size_t)C0 * DD, DD, Bl, kb * 64 + 64);
  }
  // peeled last step: stage the 128x128 mask tile into Ag/Bg instead of G(next)
  WAITV(8);
  BARM();
  __builtin_amdgcn_s_setprio(1);
  mma64(Ag, Bg, ag);
  __builtin_amdgcn_s_setprio(0);
  BARM();
  stage16(mask + (size_t)R0 * SS, SS, Ag, C0);        // mask cols C0..C0+63
  stage16(mask + (size_t)R0 * SS, SS, Bg, C0 + 64);   // mask cols C0+64..C0+127
  WAITV(8);           // L(last) landed (8 mask loads still in flight)
  BARM();
  __builtin_amdgcn_s_setprio(1);
  mma64(Al, Bl, al);  // covers mask load flight
  __builtin_amdgcn_s_setprio(0);
  WAITV(0);           // own mask loads landed
  BARM();             // everyone's mask loads landed

  const int lane = threadIdx.x & 63, wv = threadIdx.x >> 6;
  const int mm = lane & 15, quad = lane >> 4;
  float ls[2][4];
#pragma unroll
  for (int i = 0; i < 2; ++i)
#pragma unroll
    for (int r = 0; r < 4; ++r) ls[i][r] = 0.f;
#pragma unroll
  for (int i = 0; i < 2; ++i)
#pragma unroll
    for (int r = 0; r < 4; ++r) {
      const int rl = wv * 32 + i * 16 + quad * 4 + r;
      const int rg = R0 + rl;
#pragma unroll
      for (int j = 0; j < 8; ++j) {
        const int cl = j * 16 + mm;
        const float mk = mask_ld(Ag, Bg, rl, cl);
        const float scv = (ag[i][j][r] + al[i][j][r] * mk) * INV_NORM;
        const float e = __expf(scv);
        ehalf[(size_t)rg * SS + (C0 + cl)] = (f16)e;
        ls[i][r] += e;
      }
    }
#pragma unroll
  for (int d = 1; d < 16; d <<= 1)
#pragma unroll
    for (int i = 0; i < 2; ++i)
#pragma unroll
      for (int r = 0; r < 4; ++r)
        ls[i][r] += __shfl_xor(ls[i][r], d, 64);
  if (mm == 0) {
#pragma unroll
    for (int i = 0; i < 2; ++i)
#pragma unroll
      for (int r = 0; r < 4; ++r)
        atomicAdd(&lsc[R0 + wv * 32 + i * 16 + quad * 4 + r], ls[i][r]);
  }
}

// ---------------------------------------------------------------- O = (e @ V) / lsc
// Split-K=4: blockIdx.z picks a K-chunk of 1024; bf16 partials into part[z].
// Round-5: 128x64 block tiles (grid 8x32x4 = 1024), wave tile 32x64, acc 32 regs,
// LDS 24 KB -> 4 independent 4-wave blocks/CU, ALL blocks resident (16 waves/CU).
// Same per-element K accumulation order as the 128x128 version -> bit-identical.
__global__ __launch_bounds__(256, 4) void k_pv(const f16* __restrict__ ehalf,
                                               const f16* __restrict__ vt,
                                               ushort* __restrict__ part) {
  __shared__ __align__(16) f16 As[8192];
  __shared__ __align__(16) f16 Bs[4096];
  const int C0 = blockIdx.x * 64, R0 = blockIdx.y * 128, zk = blockIdx.z;
  f32x4 acc[2][4];
#pragma unroll
  for (int i = 0; i < 2; ++i)
#pragma unroll
    for (int j = 0; j < 4; ++j) acc[i][j] = (f32x4){0.f, 0.f, 0.f, 0.f};
  for (int kb = 0; kb < 16; ++kb) {
    const int k0 = zk * 1024 + kb * 64;
    __syncthreads();
    stage16 (ehalf + (size_t)R0 * SS, SS, As, k0);
    stage16h(vt    + (size_t)C0 * SS, SS, Bs, k0);
    __syncthreads();
    mma3264(As, Bs, acc);
  }
  const int lane = threadIdx.x & 63, wv = threadIdx.x >> 6;
  const int mm = lane & 15, quad = lane >> 4;
  ushort* P = part + (size_t)zk * SS * DD;
#pragma unroll
  for (int i = 0; i < 2; ++i)
#pragma unroll
    for (int j = 0; j < 4; ++j)
#pragma unroll
      for (int r = 0; r < 4; ++r)
        P[(size_t)(R0 + wv * 32 + i * 16 + quad * 4 + r) * DD + C0 + j * 16 + mm] =
            f2bf(acc[i][j][r]);
}

// ---------------------------------------------------------------- finalize
// blocks [0, 8192): att_weight = ehalf/lsc (f16x8 -> 2x float4)
// blocks [8192, 10240): att_output = sum(bf16 partials)/lsc (float4)
__global__ void k_fin(const f16* __restrict__ ehalf, const ushort* __restrict__ part,
                      const float* __restrict__ lsc, float* __restrict__ outw,
                      float* __restrict__ O) {
  const int bx = blockIdx.x;
  if (bx < 8192) {
    const size_t idx = ((size_t)bx * 256 + threadIdx.x) * 8;
    const int row = (int)(idx >> 12);
    const float inv = 1.f / lsc[row];
    const f16x8 h = *(const f16x8*)(ehalf + idx);
    float4 a = { (float)h[0] * inv, (float)h[1] * inv, (float)h[2] * inv, (float)h[3] * inv };
    float4 b = { (float)h[4] * inv, (float)h[5] * inv, (float)h[6] * inv, (float)h[7] * inv };
    *(float4*)(outw + idx) = a;
    *(float4*)(outw + idx + 4) = b;
  } else {
    const size_t idx = ((size_t)(bx - 8192) * 256 + threadIdx.x) * 4;
    const int row = (int)(idx >> 9);  // 512 floats per row
    float s0 = 0.f, s1 = 0.f, s2 = 0.f, s3 = 0.f;
#pragma unroll
    for (int p = 0; p < 4; ++p) {
      const ushort4v v = *(const ushort4v*)(part + (size_t)p * SS * DD + idx);
      s0 += bf2f(v[0]); s1 += bf2f(v[1]); s2 += bf2f(v[2]); s3 += bf2f(v[3]);
    }
    const float inv = 1.f / lsc[row];
    float4 s = { s0 * inv, s1 * inv, s2 * inv, s3 * inv };
    *(float4*)(O + idx) = s;
  }
}

// ---------------------------------------------------------------- launcher
extern "C" void kernel_launch(void* const* d_in, const int* in_sizes, int n_in,
                              void* d_out, int out_size, void* d_ws, size_t ws_size,
                              hipStream_t stream) {
  (void)in_sizes; (void)n_in; (void)out_size; (void)ws_size;
  const float* x = (const float*)d_in[0];
  const float* w[9];
  for (int i = 0; i < 9; ++i) w[i] = (const float*)d_in[1 + i];
  float* O    = (float*)d_out;            // [S,D] att_output
  float* outw = O + (size_t)SS * DD;      // [S,S] att_weight

  char* ws = (char*)d_ws;
  size_t off = 0;
  auto alloc = [&](size_t b) { void* p = ws + off; off += (b + 255) & ~(size_t)255; return p; };
  f16* xh     = (f16*)alloc((size_t)SS * DD * 2);
  f16* wt     = (f16*)alloc((size_t)9 * DD * DD * 2);
  f16* proj   = (f16*)alloc((size_t)9 * SS * DD * 2);  // ql kl qr kr qg kg qloc kloc v
  f16* vt     = (f16*)alloc((size_t)DD * SS * 2);
  f16* eL     = (f16*)alloc((size_t)SS * SS * 2);      // left probs -> att_mask (f16)
  f16* eR     = (f16*)alloc((size_t)SS * SS * 2);      // right probs; later PV partials
  f16* ehalf  = (f16*)alloc((size_t)SS * SS * 2);      // unnormalized final e in f16
  float* lsc  = (float*)alloc((size_t)SS * 4);         // final-score row sums
  ushort* part = (ushort*)eR;                          // [4][S][D] bf16 partials (eR dead)

  hipMemsetAsync(lsc, 0, (size_t)SS * 4, stream);
  k_cvt_x<<<SS * DD / 1024, 256, 0, stream>>>(x, xh);
  k_trw<<<dim3(16, 16, 9), dim3(32, 8), 0, stream>>>(w[0], w[1], w[2], w[3], w[4],
                                                     w[5], w[6], w[7], w[8], wt);
  k_proj<<<dim3(4, 32, 9), 256, 0, stream>>>(xh, wt, proj);
  k_trv<<<dim3(16, 128), dim3(32, 8), 0, stream>>>(proj + (size_t)8 * SS * DD, vt);
  k_bnd<<<dim3(528, 2), 256, 0, stream>>>(proj, eL, eR);
  k_cumsum<<<SS, 1024, 0, stream>>>(eL, eR);
  k_score<<<dim3(32, 32), 256, 0, stream>>>(proj, eL, ehalf, lsc);
  k_pv<<<dim3(8, 32, 4), 256, 0, stream>>>(ehalf, vt, part);
  k_fin<<<10240, 256, 0, stream>>>(ehalf, part, lsc, outw, O);
}

// Round 6
// 290.038 us; speedup vs baseline: 1.0781x; 1.0781x over previous
//
#include <hip/hip_runtime.h>

// DynamicAttention on MI355X (gfx950).
// Pipeline (single-pass softmaxes — scores are O(5) so exp() needs no max shift):
//   1) k_prep: x -> fp16  AND  W -> fp16 transposed (merged launch)
//   2) 9 projections via fp16 MFMA GEMM (fp32 accum); z==8 epilogue also writes
//      vt (transposed v) for the PV GEMM B-operand (k_trv launch eliminated)
//   3) boundary scores: one pass, e = exp(sc) f16 (left->eL lower tri, right->eR upper)
//      compact triangular grid (528 tiles/dir)
//   4) per-row prefix/suffix scan -> att_mask f16 into eL
//   5) final score: ping-pong pipelined (counted vmcnt(8), never drained in-loop),
//      s_setprio around MFMA clusters; mask tile staged to LDS over the last MFMA
//   6) PV: split-K=4 GEMM on ehalf@vt -> bf16 partials (alias eR)
//   7) k_fin: att_weight = ehalf/lsc; O = sum(bf16 partials)/lsc
//
// Round-2 lesson: direct-global MFMA fragments collapse (TA-bound, 8% MfmaUtil).
// Round-3 lesson: 64x64 wave tiles (less LDS traffic) regress -> not LDS-BW-bound.
// Round-4 lesson: 512-thr k_score regresses -> phase-overhead amortization beats
//   TLP; k_score reg-capped at 2 waves/SIMD (128 acc + ~120 VGPR).
// Round-5 lesson: XCD swizzle broke L3 locality (FETCH +50%); k_pv narrow C-tiles
//   doubled ehalf L3 re-reads (+18us). Traffic accounting before reshapes.

#define SS 4096
#define DD 512
#define INV_NORM 0.04419417382415922f  // 1/sqrt(512)

typedef _Float16 f16;
typedef f16 f16x8 __attribute__((ext_vector_type(8)));
typedef f16 f16x4 __attribute__((ext_vector_type(4)));
typedef float f32x4 __attribute__((ext_vector_type(4)));
typedef unsigned short ushort;
typedef ushort ushort4v __attribute__((ext_vector_type(4)));

#define GAS __attribute__((address_space(1)))
#define LAS __attribute__((address_space(3)))

// raw barrier + counted vmcnt (compiler memory fences via asm clobber)
#define BARM() asm volatile("s_barrier" ::: "memory")
#define WAITV(N) asm volatile("s_waitcnt vmcnt(" #N ")" ::: "memory")

__device__ __forceinline__ void ldsdma16(const void* g, void* l) {
  __builtin_amdgcn_global_load_lds((const GAS void*)g, (LAS void*)l, 16, 0, 0);
}

__device__ __forceinline__ ushort f2bf(float f) {  // round-to-nearest-even bf16
  unsigned u = __float_as_uint(f);
  return (ushort)((u + 0x7FFFu + ((u >> 16) & 1u)) >> 16);
}
__device__ __forceinline__ float bf2f(ushort h) {
  return __uint_as_float((unsigned)h << 16);
}

// Stage a 128x64 f16 tile (rows x k) from row-major [*, ldk] global into LDS.
// 16B-chunk XOR swizzle: logical chunk q of row r stored at slot (q ^ (r&7)).
__device__ __forceinline__ void stage16(const f16* __restrict__ src, int ldk, f16* lds, int k0) {
  const int tid  = threadIdx.x;
  const int lane = tid & 63;
  const int wv   = tid >> 6;
  const int rb   = wv * 8 + (lane >> 3);
  const int cs   = lane & 7;
#pragma unroll
  for (int c = 0; c < 4; ++c) {
    const int r = c * 32 + rb;
    const int q = cs ^ (r & 7);
    ldsdma16(src + (size_t)r * ldk + k0 + q * 8, lds + c * 2048 + wv * 512);
  }
}

// MFMA fragment load: lane holds [m=lane&15][k=(lane>>4)*8 + 0..7].
__device__ __forceinline__ f16x8 fragld(const f16* lds, int r0, int qb) {
  const int lane = threadIdx.x & 63;
  const int r = r0 + (lane & 15);
  const int q = (qb + (lane >> 4)) ^ (r & 7);
  return *(const f16x8*)(lds + r * 64 + q * 8);
}

// Accumulate one BK=64 step: this wave's 32 rows x 128 cols (2x8 16x16 fragments).
__device__ __forceinline__ void mma64(const f16* As, const f16* Bs, f32x4 acc[2][8]) {
  const int wv = threadIdx.x >> 6;
#pragma unroll
  for (int ks = 0; ks < 2; ++ks) {
    const f16x8 a0 = fragld(As, wv * 32,      ks * 4);
    const f16x8 a1 = fragld(As, wv * 32 + 16, ks * 4);
#pragma unroll
    for (int j = 0; j < 8; ++j) {
      const f16x8 b = fragld(Bs, j * 16, ks * 4);
      acc[0][j] = __builtin_amdgcn_mfma_f32_16x16x32_f16(a0, b, acc[0][j], 0, 0, 0);
      acc[1][j] = __builtin_amdgcn_mfma_f32_16x16x32_f16(a1, b, acc[1][j], 0, 0, 0);
    }
  }
}

// ---------------------------------------------------------------- prep (merged)
// blocks [0, 2048): x -> fp16 (float4 -> f16x4)
// blocks [2048, 4352): W transpose+convert, 32x32 tiles via LDS
__global__ void k_prep(const float* __restrict__ x, const float* w0, const float* w1,
                       const float* w2, const float* w3, const float* w4, const float* w5,
                       const float* w6, const float* w7, const float* w8,
                       f16* __restrict__ xh, f16* __restrict__ wt) {
  const int bx = blockIdx.x;
  if (bx < 2048) {
    const size_t i = ((size_t)bx * 256 + threadIdx.x) * 4;
    const float4 f = *(const float4*)(x + i);
    f16x4 h = { (f16)f.x, (f16)f.y, (f16)f.z, (f16)f.w };
    *(f16x4*)(xh + i) = h;
    return;
  }
  const int idx = bx - 2048;              // [0, 2304)
  const int bz = idx >> 8;                // weight index 0..8
  const int rem = idx & 255;
  const int n0 = (rem & 15) * 32, k0 = (rem >> 4) * 32;
  const float* srcs[9] = {w0, w1, w2, w3, w4, w5, w6, w7, w8};
  const float* src = srcs[bz];
  f16* dst = wt + (size_t)bz * DD * DD;
  __shared__ float t[32][33];
  const int tx = threadIdx.x & 31, ty = threadIdx.x >> 5;  // 32 x 8
#pragma unroll
  for (int i = 0; i < 32; i += 8)
    t[ty + i][tx] = src[(size_t)(k0 + ty + i) * DD + n0 + tx];
  __syncthreads();
#pragma unroll
  for (int i = 0; i < 32; i += 8)
    dst[(size_t)(n0 + ty + i) * DD + k0 + tx] = (f16)t[tx][ty + i];
}

// ---------------------------------------------------------------- projections
// z==8 (the v projection) additionally writes vt[n][s] = v[s][n] so the k_trv
// launch disappears. 64 scattered 2B stores per thread, only on 128/1152 blocks.
__global__ __launch_bounds__(256, 3) void k_proj(const f16* __restrict__ xh,
                                                 const f16* __restrict__ wt,
                                                 f16* __restrict__ proj,
                                                 f16* __restrict__ vt) {
  __shared__ __align__(16) f16 As[8192];
  __shared__ __align__(16) f16 Bs[8192];
  const int z = blockIdx.z;
  const f16* B = wt + (size_t)z * DD * DD;
  f16* C = proj + (size_t)z * SS * DD;
  const int R0 = blockIdx.y * 128, C0 = blockIdx.x * 128;
  f32x4 acc[2][8];
#pragma unroll
  for (int i = 0; i < 2; ++i)
#pragma unroll
    for (int j = 0; j < 8; ++j) acc[i][j] = (f32x4){0.f, 0.f, 0.f, 0.f};
  for (int kb = 0; kb < DD / 64; ++kb) {
    __syncthreads();
    stage16(xh + (size_t)R0 * DD, DD, As, kb * 64);
    stage16(B  + (size_t)C0 * DD, DD, Bs, kb * 64);
    __syncthreads();
    mma64(As, Bs, acc);
  }
  const int lane = threadIdx.x & 63, wv = threadIdx.x >> 6;
  const int mm = lane & 15, quad = lane >> 4;
#pragma unroll
  for (int i = 0; i < 2; ++i)
#pragma unroll
    for (int j = 0; j < 8; ++j)
#pragma unroll
      for (int r = 0; r < 4; ++r)
        C[(size_t)(R0 + wv * 32 + i * 16 + quad * 4 + r) * DD + C0 + j * 16 + mm] =
            (f16)acc[i][j][r];
  if (z == 8) {  // also emit transposed v
#pragma unroll
    for (int i = 0; i < 2; ++i)
#pragma unroll
      for (int j = 0; j < 8; ++j)
#pragma unroll
        for (int r = 0; r < 4; ++r)
          vt[(size_t)(C0 + j * 16 + mm) * SS + (R0 + wv * 32 + i * 16 + quad * 4 + r)] =
              (f16)acc[i][j][r];
  }
}

// ---------------------------------------------------------------- boundaries
// Compact triangular grid: 528 tiles per dir. dir 0 = left (valid c<=r, ->eL),
// dir 1 = right (valid c>=r, ->eR).  e = exp(sc) f16, no max shift (|sc| <~ 6).
__global__ __launch_bounds__(256, 3) void k_bnd(const f16* __restrict__ proj,
                                                f16* __restrict__ eL,
                                                f16* __restrict__ eR) {
  const int t = blockIdx.x, dir = blockIdx.y;
  int rbk = (int)((sqrtf(8.f * t + 1.f) - 1.f) * 0.5f);
  while ((rbk + 1) * (rbk + 2) / 2 <= t) ++rbk;
  while (rbk * (rbk + 1) / 2 > t) --rbk;
  int jt = t - rbk * (rbk + 1) / 2;           // jt <= rbk (lower triangle)
  if (dir) { jt = 31 - jt; rbk = 31 - rbk; }  // mirror -> jt >= rbk
  __shared__ __align__(16) f16 As[8192];
  __shared__ __align__(16) f16 Bs[8192];
  const f16* q  = proj + (size_t)(dir ? 2 : 0) * SS * DD;
  const f16* kp = proj + (size_t)(dir ? 3 : 1) * SS * DD;
  const int R0 = rbk * 128, C0 = jt * 128;
  f32x4 acc[2][8];
#pragma unroll
  for (int i = 0; i < 2; ++i)
#pragma unroll
    for (int j = 0; j < 8; ++j) acc[i][j] = (f32x4){0.f, 0.f, 0.f, 0.f};
  for (int kb = 0; kb < DD / 64; ++kb) {
    __syncthreads();
    stage16(q  + (size_t)R0 * DD, DD, As, kb * 64);
    stage16(kp + (size_t)C0 * DD, DD, Bs, kb * 64);
    __syncthreads();
    mma64(As, Bs, acc);
  }
  const int lane = threadIdx.x & 63, wv = threadIdx.x >> 6;
  const int mm = lane & 15, quad = lane >> 4;
  const bool diag = (jt == rbk);
  f16* outp = dir ? eR : eL;
#pragma unroll
  for (int i = 0; i < 2; ++i)
#pragma unroll
    for (int r = 0; r < 4; ++r) {
      const int rl = wv * 32 + i * 16 + quad * 4 + r;
#pragma unroll
      for (int j = 0; j < 8; ++j) {
        const int cl = j * 16 + mm;
        const float sc = acc[i][j][r] * INV_NORM;
        const bool bad = diag && (dir ? (cl < rl) : (cl > rl));
        const float e = bad ? 0.f : __expf(sc);
        outp[(size_t)(R0 + rl) * SS + (C0 + cl)] = (f16)e;
      }
    }
}

// ---------------------------------------------------------------- mask build
// One 1024-thread block per row i. Thread t owns f16x4 chunk at j=4t (coalesced).
// Loads are conditional: eL only where chunk intersects j<=i, eR only where j>=i.
__global__ __launch_bounds__(1024) void k_cumsum(f16* __restrict__ eL,
                                                 const f16* __restrict__ eR) {
  const int i = blockIdx.x;
  const int tid = threadIdx.x, lane = tid & 63, wv = tid >> 6;  // 16 waves
  __shared__ float wsL[16], wsR[16];
  const int j0 = tid * 4;

  // ---- left: e values valid for j<=i
  float pl[4] = {0.f, 0.f, 0.f, 0.f};
  if (j0 <= i) {
    const f16x4 hl = *(const f16x4*)(eL + (size_t)i * SS + j0);
#pragma unroll
    for (int u = 0; u < 4; ++u) pl[u] = (j0 + u <= i) ? (float)hl[u] : 0.f;
  }
#pragma unroll
  for (int u = 1; u < 4; ++u) pl[u] += pl[u - 1];
  const float Tl = pl[3];
  float sl = Tl;
#pragma unroll
  for (int d = 1; d < 64; d <<= 1) {
    const float o = __shfl_up(sl, (unsigned)d, 64);
    if (lane >= d) sl += o;
  }
  if (lane == 63) wsL[wv] = sl;

  // ---- right: e values valid for j>=i
  float rr[4] = {0.f, 0.f, 0.f, 0.f}, pr[4];
  if (j0 + 3 >= i) {
    const f16x4 hr = *(const f16x4*)(eR + (size_t)i * SS + j0);
#pragma unroll
    for (int u = 0; u < 4; ++u) rr[u] = (j0 + u >= i) ? (float)hr[u] : 0.f;
  }
  pr[0] = rr[0];
#pragma unroll
  for (int u = 1; u < 4; ++u) pr[u] = pr[u - 1] + rr[u];
  const float Tr = pr[3];
  float sr = Tr;
#pragma unroll
  for (int d = 1; d < 64; d <<= 1) {
    const float o = __shfl_up(sr, (unsigned)d, 64);
    if (lane >= d) sr += o;
  }
  if (lane == 63) wsR[wv] = sr;

  __syncthreads();
  float offL = 0.f, totL = 0.f, offR = 0.f, totR = 0.f;
#pragma unroll
  for (int ww = 0; ww < 16; ++ww) {
    const float a = wsL[ww], b = wsR[ww];
    if (ww < wv) { offL += a; offR += b; }
    totL += a; totR += b;
  }
  const float exL = offL + sl - Tl;        // exclusive prefix before this thread
  const float exR = offR + sr - Tr;
  const float invL = 1.f / totL, invR = 1.f / totR;

  f16x4 out;
#pragma unroll
  for (int u = 0; u < 4; ++u) {
    const int j = j0 + u;
    const float cdfL = (exL + pl[u]) * invL;                 // inclusive prefix
    const float pre  = exR + pr[u];
    const float cdfR = (totR - pre + rr[u]) * invR;          // inclusive suffix
    const float m = (j < i) ? cdfL : ((j > i) ? cdfR : 1.f);
    out[u] = (f16)m;
  }
  *(f16x4*)(eL + (size_t)i * SS + j0) = out;
}

// ---------------------------------------------------------------- final scores
// Single pass: sc = (qg.kg^T + (qloc.kloc^T)*mask)/norm; e=exp(sc) -> ehalf (f16);
// rowsum -> lsc via atomicAdd.
// Ping-pong pipeline (round-1 verified): G pair and L pair staged alternately with
// counted vmcnt(8); mask tile staged into dead Ag/Bg during the final L-MFMA.
// Round-6: s_setprio around MFMA only (no swizzle — round-5 showed it breaks L3
// locality); default blockIdx order restored.
__device__ __forceinline__ float mask_ld(const f16* Am, const f16* Bm, int r, int c) {
  const f16* b = (c < 64) ? Am : Bm;
  const int cc = c & 63;
  const int q = (cc >> 3) ^ (r & 7);
  return (float)b[r * 64 + q * 8 + (cc & 7)];
}

__global__ __launch_bounds__(256, 2) void k_score(const f16* __restrict__ proj,
                                                  const f16* __restrict__ mask,
                                                  f16* __restrict__ ehalf,
                                                  float* __restrict__ lsc) {
  __shared__ __align__(16) f16 Ag[8192];
  __shared__ __align__(16) f16 Bg[8192];
  __shared__ __align__(16) f16 Al[8192];
  __shared__ __align__(16) f16 Bl[8192];
  const int jt = blockIdx.x, rbk = blockIdx.y;
  const f16* qg = proj + (size_t)4 * SS * DD;
  const f16* kg = proj + (size_t)5 * SS * DD;
  const f16* ql = proj + (size_t)6 * SS * DD;
  const f16* kl = proj + (size_t)7 * SS * DD;
  const int R0 = rbk * 128, C0 = jt * 128;
  f32x4 ag[2][8], al[2][8];
#pragma unroll
  for (int i = 0; i < 2; ++i)
#pragma unroll
    for (int j = 0; j < 8; ++j) {
      ag[i][j] = (f32x4){0.f, 0.f, 0.f, 0.f};
      al[i][j] = (f32x4){0.f, 0.f, 0.f, 0.f};
    }
  // prologue: both pairs for kb=0 in flight (16 outstanding/thread)
  stage16(qg + (size_t)R0 * DD, DD, Ag, 0);
  stage16(kg + (size_t)C0 * DD, DD, Bg, 0);
  stage16(ql + (size_t)R0 * DD, DD, Al, 0);
  stage16(kl + (size_t)C0 * DD, DD, Bl, 0);
  for (int kb = 0; kb < DD / 64 - 1; ++kb) {
    WAITV(8);           // G(kb) landed; L(kb) still in flight
    BARM();
    __builtin_amdgcn_s_setprio(1);
    mma64(Ag, Bg, ag);
    __builtin_amdgcn_s_setprio(0);
    BARM();             // all waves done reading G pair
    stage16(qg + (size_t)R0 * DD, DD, Ag, kb * 64 + 64);   // G(kb+1), flies over mma_l
    stage16(kg + (size_t)C0 * DD, DD, Bg, kb * 64 + 64);
    WAITV(8);           // L(kb) landed; G(kb+1) in flight
    BARM();
    __builtin_amdgcn_s_setprio(1);
    mma64(Al, Bl, al);
    __builtin_amdgcn_s_setprio(0);
    BARM();             // all waves done reading L pair
    stage16(ql + (size_t)R0 * DD, DD, Al, kb * 64 + 64);   // L(kb+1), flies over next mma_g
    stage16(kl + (size_t)C0 * DD, DD, Bl, kb * 64 + 64);
  }
  // peeled last step: stage the 128x128 mask tile into Ag/Bg instead of G(next)
  WAITV(8);
  BARM();
  __builtin_amdgcn_s_setprio(1);
  mma64(Ag, Bg, ag);
  __builtin_amdgcn_s_setprio(0);
  BARM();
  stage16(mask + (size_t)R0 * SS, SS, Ag, C0);        // mask cols C0..C0+63
  stage16(mask + (size_t)R0 * SS, SS, Bg, C0 + 64);   // mask cols C0+64..C0+127
  WAITV(8);           // L(last) landed (8 mask loads still in flight)
  BARM();
  __builtin_amdgcn_s_setprio(1);
  mma64(Al, Bl, al);  // covers mask load flight
  __builtin_amdgcn_s_setprio(0);
  WAITV(0);           // own mask loads landed
  BARM();             // everyone's mask loads landed

  const int lane = threadIdx.x & 63, wv = threadIdx.x >> 6;
  const int mm = lane & 15, quad = lane >> 4;
  float ls[2][4];
#pragma unroll
  for (int i = 0; i < 2; ++i)
#pragma unroll
    for (int r = 0; r < 4; ++r) ls[i][r] = 0.f;
#pragma unroll
  for (int i = 0; i < 2; ++i)
#pragma unroll
    for (int r = 0; r < 4; ++r) {
      const int rl = wv * 32 + i * 16 + quad * 4 + r;
      const int rg = R0 + rl;
#pragma unroll
      for (int j = 0; j < 8; ++j) {
        const int cl = j * 16 + mm;
        const float mk = mask_ld(Ag, Bg, rl, cl);
        const float scv = (ag[i][j][r] + al[i][j][r] * mk) * INV_NORM;
        const float e = __expf(scv);
        ehalf[(size_t)rg * SS + (C0 + cl)] = (f16)e;
        ls[i][r] += e;
      }
    }
#pragma unroll
  for (int d = 1; d < 16; d <<= 1)
#pragma unroll
    for (int i = 0; i < 2; ++i)
#pragma unroll
      for (int r = 0; r < 4; ++r)
        ls[i][r] += __shfl_xor(ls[i][r], d, 64);
  if (mm == 0) {
#pragma unroll
    for (int i = 0; i < 2; ++i)
#pragma unroll
      for (int r = 0; r < 4; ++r)
        atomicAdd(&lsc[R0 + wv * 32 + i * 16 + quad * 4 + r], ls[i][r]);
  }
}

// ---------------------------------------------------------------- O = (e @ V) / lsc
// Split-K=4: blockIdx.z picks a K-chunk of 1024; bf16 partials into part[z].
// (round-1 tiling restored: 128x128 tiles minimize ehalf/vt L3 re-reads)
__global__ __launch_bounds__(256, 4) void k_pv(const f16* __restrict__ ehalf,
                                               const f16* __restrict__ vt,
                                               ushort* __restrict__ part) {
  __shared__ __align__(16) f16 As[8192];
  __shared__ __align__(16) f16 Bs[8192];
  const int C0 = blockIdx.x * 128, R0 = blockIdx.y * 128, zk = blockIdx.z;
  f32x4 acc[2][8];
#pragma unroll
  for (int i = 0; i < 2; ++i)
#pragma unroll
    for (int j = 0; j < 8; ++j) acc[i][j] = (f32x4){0.f, 0.f, 0.f, 0.f};
  for (int kb = 0; kb < 16; ++kb) {
    const int k0 = zk * 1024 + kb * 64;
    __syncthreads();
    stage16(ehalf + (size_t)R0 * SS, SS, As, k0);
    stage16(vt    + (size_t)C0 * SS, SS, Bs, k0);
    __syncthreads();
    mma64(As, Bs, acc);
  }
  const int lane = threadIdx.x & 63, wv = threadIdx.x >> 6;
  const int mm = lane & 15, quad = lane >> 4;
  ushort* P = part + (size_t)zk * SS * DD;
#pragma unroll
  for (int i = 0; i < 2; ++i)
#pragma unroll
    for (int j = 0; j < 8; ++j)
#pragma unroll
      for (int r = 0; r < 4; ++r)
        P[(size_t)(R0 + wv * 32 + i * 16 + quad * 4 + r) * DD + C0 + j * 16 + mm] =
            f2bf(acc[i][j][r]);
}

// ---------------------------------------------------------------- finalize
// blocks [0, 8192): att_weight = ehalf/lsc (f16x8 -> 2x float4)
// blocks [8192, 10240): att_output = sum(bf16 partials)/lsc (float4)
__global__ void k_fin(const f16* __restrict__ ehalf, const ushort* __restrict__ part,
                      const float* __restrict__ lsc, float* __restrict__ outw,
                      float* __restrict__ O) {
  const int bx = blockIdx.x;
  if (bx < 8192) {
    const size_t idx = ((size_t)bx * 256 + threadIdx.x) * 8;
    const int row = (int)(idx >> 12);
    const float inv = 1.f / lsc[row];
    const f16x8 h = *(const f16x8*)(ehalf + idx);
    float4 a = { (float)h[0] * inv, (float)h[1] * inv, (float)h[2] * inv, (float)h[3] * inv };
    float4 b = { (float)h[4] * inv, (float)h[5] * inv, (float)h[6] * inv, (float)h[7] * inv };
    *(float4*)(outw + idx) = a;
    *(float4*)(outw + idx + 4) = b;
  } else {
    const size_t idx = ((size_t)(bx - 8192) * 256 + threadIdx.x) * 4;
    const int row = (int)(idx >> 9);  // 512 floats per row
    float s0 = 0.f, s1 = 0.f, s2 = 0.f, s3 = 0.f;
#pragma unroll
    for (int p = 0; p < 4; ++p) {
      const ushort4v v = *(const ushort4v*)(part + (size_t)p * SS * DD + idx);
      s0 += bf2f(v[0]); s1 += bf2f(v[1]); s2 += bf2f(v[2]); s3 += bf2f(v[3]);
    }
    const float inv = 1.f / lsc[row];
    float4 s = { s0 * inv, s1 * inv, s2 * inv, s3 * inv };
    *(float4*)(O + idx) = s;
  }
}

// ---------------------------------------------------------------- launcher
extern "C" void kernel_launch(void* const* d_in, const int* in_sizes, int n_in,
                              void* d_out, int out_size, void* d_ws, size_t ws_size,
                              hipStream_t stream) {
  (void)in_sizes; (void)n_in; (void)out_size; (void)ws_size;
  const float* x = (const float*)d_in[0];
  const float* w[9];
  for (int i = 0; i < 9; ++i) w[i] = (const float*)d_in[1 + i];
  float* O    = (float*)d_out;            // [S,D] att_output
  float* outw = O + (size_t)SS * DD;      // [S,S] att_weight

  char* ws = (char*)d_ws;
  size_t off = 0;
  auto alloc = [&](size_t b) { void* p = ws + off; off += (b + 255) & ~(size_t)255; return p; };
  f16* xh     = (f16*)alloc((size_t)SS * DD * 2);
  f16* wt     = (f16*)alloc((size_t)9 * DD * DD * 2);
  f16* proj   = (f16*)alloc((size_t)9 * SS * DD * 2);  // ql kl qr kr qg kg qloc kloc v
  f16* vt     = (f16*)alloc((size_t)DD * SS * 2);
  f16* eL     = (f16*)alloc((size_t)SS * SS * 2);      // left probs -> att_mask (f16)
  f16* eR     = (f16*)alloc((size_t)SS * SS * 2);      // right probs; later PV partials
  f16* ehalf  = (f16*)alloc((size_t)SS * SS * 2);      // unnormalized final e in f16
  float* lsc  = (float*)alloc((size_t)SS * 4);         // final-score row sums
  ushort* part = (ushort*)eR;                          // [4][S][D] bf16 partials (eR dead)

  hipMemsetAsync(lsc, 0, (size_t)SS * 4, stream);
  k_prep<<<4352, 256, 0, stream>>>(x, w[0], w[1], w[2], w[3], w[4], w[5], w[6], w[7], w[8],
                                   xh, wt);
  k_proj<<<dim3(4, 32, 9), 256, 0, stream>>>(xh, wt, proj, vt);
  k_bnd<<<dim3(528, 2), 256, 0, stream>>>(proj, eL, eR);
  k_cumsum<<<SS, 1024, 0, stream>>>(eL, eR);
  k_score<<<dim3(32, 32), 256, 0, stream>>>(proj, eL, ehalf, lsc);
  k_pv<<<dim3(4, 32, 4), 256, 0, stream>>>(ehalf, vt, part);
  k_fin<<<10240, 256, 0, stream>>>(ehalf, part, lsc, outw, O);
}